// Round 15
// baseline (76.884 us; speedup 1.0000x reference)
//
#include <hip/hip_runtime.h>
#include <math.h>

#define B_ 4
#define H_ 12
#define N_ 1025
#define D_ 64
#define HID_ 32
#define TBL_ 3969            // (2*32-1)^2
#define NQT 17               // 64-row tiles in both q and k
#define NBLK (B_ * H_ * NQT) // 816, divisible by 8
#define LOG2E 1.44269504f
#define THR_ 12.0f           // defer-max threshold (log2 domain); p <= 2^12 fits f16

typedef _Float16 half8 __attribute__((ext_vector_type(8)));
typedef __fp16 fp16x2 __attribute__((ext_vector_type(2)));
typedef float f32x4 __attribute__((ext_vector_type(4)));
typedef float f32x4u __attribute__((ext_vector_type(4), aligned(4)));  // 4B-aligned float4

#if defined(__has_builtin)
#if __has_builtin(__builtin_amdgcn_exp2f)
#define EX2 __builtin_amdgcn_exp2f
#else
#define EX2 exp2f
#endif
#else
#define EX2 exp2f
#endif

// ws layout (bytes):
//   akT @ 0        : 48*1088*4 = 208896   (also the pad for btR's small underrun)
//   btR @ 208896   : 12*3969*4 = 190512   (REVERSED bias table: btR[h][y]=bt[h][3968-y])
//   Kf  @ 399408   : 48*17*4096*2 = 6684672
//   Vf  @ 7084080  : 6684672              (end 13768752; tail-tile gather overruns stay in ws)
#define AKT_OFF 0
#define BTR_OFF 208896
#define KF_OFF 399408
#define VF_OFF 7084080

__device__ __forceinline__ void stage16(const _Float16* gsrc, _Float16* ldst) {
    __builtin_amdgcn_global_load_lds(
        (const __attribute__((address_space(1))) void*)gsrc,
        (__attribute__((address_space(3))) void*)ldst, 16, 0, 0);
}

// ---------------- prep: K/V -> f16 fragment-order tiles (V via LDS transpose),
// akT = sigmoid(gamma)*log2e*mu_k, btR = REVERSED MLP bias table (per-head)
__global__ __launch_bounds__(256) void prep(
    const float* __restrict__ K, const float* __restrict__ V,
    const float* __restrict__ MU, const float* __restrict__ GAMMA,
    const float* __restrict__ rel, const float* __restrict__ w1,
    const float* __restrict__ b1, const float* __restrict__ w2,
    _Float16* __restrict__ Kf, _Float16* __restrict__ Vf,
    float* __restrict__ akT, float* __restrict__ btR) {
    const int bid = blockIdx.x;
    const int tid = threadIdx.x;
    if (bid < NBLK) {
        __shared__ float Vls[64 * 65];  // [d][k], pad 65 (2-way banks max)
        const int bh = bid / NQT, kt = bid % NQT;
        const size_t base = (size_t)bh * (N_ * D_);
        const int k0 = kt * 64;
        // V rows: coalesced global read -> transposed LDS scatter
#pragma unroll
        for (int it = 0; it < 4; ++it) {
            const int idx = it * 256 + tid;
            const int kr = idx >> 4, c4 = (idx & 15) << 2;
            const int kg = k0 + kr;
            float4 v4 = make_float4(0, 0, 0, 0);
            if (kg < N_) v4 = *(const float4*)(V + base + (size_t)kg * D_ + c4);
            Vls[(c4 + 0) * 65 + kr] = v4.x;
            Vls[(c4 + 1) * 65 + kr] = v4.y;
            Vls[(c4 + 2) * 65 + kr] = v4.z;
            Vls[(c4 + 3) * 65 + kr] = v4.w;
        }
        __syncthreads();
        const int lane = tid & 63, lq = lane & 15, g = lane >> 4;
        const int fbh = tid >> 6;
        const size_t tb = (size_t)(bh * NQT + kt) * 4096;
#pragma unroll
        for (int x = 0; x < 2; ++x) {
            const int fb = fbh + x * 4;
            {   // V fragment fb = kh*4+dg from LDS
                const int kh = fb >> 2, dg = fb & 3;
                const float* vp = &Vls[(dg * 16 + lq) * 65 + kh * 32 + g * 8];
                half8 v8;
#pragma unroll
                for (int j = 0; j < 8; ++j) v8[j] = (_Float16)vp[j];
                *(half8*)&Vf[tb + fb * 512 + lane * 8] = v8;
            }
            {   // K fragment fb = kg2*2+dh, direct
                const int row = k0 + (fb >> 1) * 16 + lq;
                const int col = (fb & 1) * 32 + g * 8;
                half8 k8;
                if (row < N_) {
                    const float4* p = (const float4*)(K + base + (size_t)row * D_ + col);
                    float4 a = p[0], b = p[1];
                    k8[0] = (_Float16)a.x; k8[1] = (_Float16)a.y;
                    k8[2] = (_Float16)a.z; k8[3] = (_Float16)a.w;
                    k8[4] = (_Float16)b.x; k8[5] = (_Float16)b.y;
                    k8[6] = (_Float16)b.z; k8[7] = (_Float16)b.w;
                } else {
#pragma unroll
                    for (int j = 0; j < 8; ++j) k8[j] = (_Float16)0.f;
                }
                *(half8*)&Kf[tb + fb * 512 + lane * 8] = k8;
            }
        }
        if (tid < 64) {
            const int kk = k0 + tid;
            const int h = bh % H_;
            const float sgl = LOG2E / (1.f + __expf(-GAMMA[h]));
            float a = 0.f;
            if (kk >= 1 && kk < N_) a = sgl * MU[((size_t)bh * 2 + 1) * N_ + kk];
            akT[bh * 1088 + kk] = a;
        }
    } else {
        const int i = (bid - NBLK) * 256 + tid;
        if (i < TBL_) {
            const float x0 = rel[2 * i + 0], x1 = rel[2 * i + 1];
            float acc[H_];
#pragma unroll
            for (int h = 0; h < H_; ++h) acc[h] = 0.f;
#pragma unroll
            for (int j = 0; j < HID_; ++j) {
                float t = fmaf(x0, w1[j], fmaf(x1, w1[HID_ + j], b1[j]));
                float gl = 0.5f * t * (1.f + erff(t * 0.7071067811865475f));  // exact gelu
#pragma unroll
                for (int h = 0; h < H_; ++h) acc[h] = fmaf(gl, w2[j * H_ + h], acc[h]);
            }
#pragma unroll
            for (int h = 0; h < H_; ++h) btR[h * TBL_ + (TBL_ - 1 - i)] = acc[h];
        }
    }
}

// inlined, spill-free bias gather (constant-indexed array writes only)
#define GATHER_BIAS(BT)                                                          \
    {                                                                            \
        _Pragma("unroll") for (int kg = 0; kg < 4; ++kg) {                       \
            const int off = boff4[kg];                                           \
            if (kg & 1) { /* never crosses a 32-row boundary */                  \
                f32x4u f4 = *(const f32x4u*)(btb + off);                         \
                BT[kg * 4 + 0] = f4[0]; BT[kg * 4 + 1] = f4[1];                  \
                BT[kg * 4 + 2] = f4[2]; BT[kg * 4 + 3] = f4[3];                  \
            } else { /* g==0 lanes cross: r0 separate, r1..r3 at +32 elems */    \
                const bool cross = (g == 0);                                     \
                f32x4u f4 = *(const f32x4u*)(btb + off + (cross ? 128 : 0));     \
                const float s0v = *(const float*)(btb + off);                    \
                BT[kg * 4 + 0] = s0v;                                            \
                BT[kg * 4 + 1] = cross ? f4[0] : f4[1];                          \
                BT[kg * 4 + 2] = cross ? f4[1] : f4[2];                          \
                BT[kg * 4 + 3] = cross ? f4[2] : f4[3];                          \
            }                                                                    \
            boff4[kg] += 504;                                                    \
        }                                                                        \
    }

// ---------------- fused flash attention, f16 MFMA, DMA-staged fragment tiles
// (round-12 structure) + one-tile-ahead bias/ak prefetch, spill-free.
__global__ __launch_bounds__(256, 4) void flex_attn(
    const float* __restrict__ Q, const _Float16* __restrict__ Kf,
    const _Float16* __restrict__ Vf, const float* __restrict__ MU,
    const float* __restrict__ GAMMA, const char* __restrict__ btb,  // = ws + BTR_OFF
    const float* __restrict__ akT, float* __restrict__ OUT) {
    __shared__ __align__(16) _Float16 Ks[2][4096];
    __shared__ __align__(16) _Float16 Vs[2][4096];
    __shared__ __align__(16) _Float16 Pl[4][1024];  // [wave][16 q][64 k] XOR-swizzled

    const int bid = blockIdx.x;
    const int swz0 = (bid & 7) * (NBLK / 8) + (bid >> 3);  // bijective XCD swizzle
    const int bh = swz0 / NQT;
    const int qt = swz0 % NQT;
    const int h = bh % H_;
    const int tid = threadIdx.x;
    const int w = tid >> 6;
    const int lane = tid & 63;
    const int lq = lane & 15;
    const int g = lane >> 4;

    const size_t base = (size_t)bh * (N_ * D_);
    const float sg = LOG2E / (1.f + __expf(-GAMMA[h]));

    const int qrow = qt * 64 + w * 16 + lq;
    const bool qv = qrow < N_;

    // Q fragment (B-operand of swapped QK^T), scale = log2e/sqrt(64)
    half8 qf[2];
#pragma unroll
    for (int dh = 0; dh < 2; ++dh) {
        float4 t0 = make_float4(0, 0, 0, 0), t1 = t0;
        if (qv) {
            const float4* qp = (const float4*)(Q + base + (size_t)qrow * D_ + dh * 32 + g * 8);
            t0 = qp[0]; t1 = qp[1];
        }
        const float qs = 0.125f * LOG2E;
        half8 q8;
        q8[0] = (_Float16)(t0.x * qs); q8[1] = (_Float16)(t0.y * qs);
        q8[2] = (_Float16)(t0.z * qs); q8[3] = (_Float16)(t0.w * qs);
        q8[4] = (_Float16)(t1.x * qs); q8[5] = (_Float16)(t1.y * qs);
        q8[6] = (_Float16)(t1.z * qs); q8[7] = (_Float16)(t1.w * qs);
        qf[dh] = q8;
    }

    const bool qb = qv && (qrow >= 1);
    const float qbf = qb ? 1.f : 0.f;
    float aq = 0.f;
    int cq = 0;
    if (qb) {
        const int pq = qrow - 1;
        cq = (pq >> 5) * 63 + (pq & 31);
        aq = sg * MU[(size_t)bh * 2 * N_ + qrow];  // sg*log2e*mu_q
    }
    // REVERSED table: value(ck) = btR[h*TBL + 1984 - cq + ck] -> forward-consecutive
    // in ck. Quads consecutive except (kg even && g==0): r0 separate, r1..3 at +32.
    // Per-tile recurrence: ck += 126 -> byte offset += 504.
    int boff4[4];
#pragma unroll
    for (int kg = 0; kg < 4; ++kg) {
        const int pk0 = kg * 16 + g * 4 - 1;              // tile 0
        const int ck0 = (pk0 >> 5) * 63 + (pk0 & 31);     // arith shift: ck0(-1) = -32
        boff4[kg] = (h * TBL_ + 1984 - cq + ck0) * 4;
    }
    const float* akb = akT + bh * 1088;
    const _Float16* kfb = Kf + (size_t)bh * NQT * 4096;
    const _Float16* vfb = Vf + (size_t)bh * NQT * 4096;

    f32x4 o[4];
    const f32x4 zz = {0.f, 0.f, 0.f, 0.f};
#pragma unroll
    for (int dg = 0; dg < 4; ++dg) o[dg] = zz;
    float m = 0.f, lsum = 0.f;

    // prologue: stage tile 0 into buf 0; gather tile 0's bias/ak into current regs
    stage16(kfb + (2 * w + 0) * 512 + lane * 8, &Ks[0][(2 * w + 0) * 512]);
    stage16(kfb + (2 * w + 1) * 512 + lane * 8, &Ks[0][(2 * w + 1) * 512]);
    stage16(vfb + (2 * w + 0) * 512 + lane * 8, &Vs[0][(2 * w + 0) * 512]);
    stage16(vfb + (2 * w + 1) * 512 + lane * 8, &Vs[0][(2 * w + 1) * 512]);
    float btc[16];
    GATHER_BIAS(btc)
    f32x4 akc[4];
#pragma unroll
    for (int kg = 0; kg < 4; ++kg) akc[kg] = *(const f32x4*)(akb + kg * 16 + g * 4);
    __syncthreads();

    const int pswz = (lq & 7) << 4;
    char* plw = (char*)&Pl[w][0];

    for (int t = 0; t < NQT; ++t) {
        const int buf = t & 1;

        // ---- stage next tile into the other buffer
        if (t + 1 < NQT) {
            const _Float16* kn = kfb + (size_t)(t + 1) * 4096;
            const _Float16* vn = vfb + (size_t)(t + 1) * 4096;
            stage16(kn + (2 * w + 0) * 512 + lane * 8, &Ks[buf ^ 1][(2 * w + 0) * 512]);
            stage16(kn + (2 * w + 1) * 512 + lane * 8, &Ks[buf ^ 1][(2 * w + 1) * 512]);
            stage16(vn + (2 * w + 0) * 512 + lane * 8, &Vs[buf ^ 1][(2 * w + 0) * 512]);
            stage16(vn + (2 * w + 1) * 512 + lane * 8, &Vs[buf ^ 1][(2 * w + 1) * 512]);
        }

        // ---- prefetch NEXT tile's bias/ak (consumed next iteration, after the
        //      barrier's vmcnt drain -> zero exposed latency). Spill-free:
        //      constant-indexed locals only. Tail-tile reads stay inside ws.
        float btn[16];
        GATHER_BIAS(btn)
        f32x4 akn[4];
        {
            const int kt1 = (t + 1 < NQT) ? (t + 1) * 64 : t * 64;
#pragma unroll
            for (int kg = 0; kg < 4; ++kg)
                akn[kg] = *(const f32x4*)(akb + kt1 + kg * 16 + g * 4);
        }

        // ---- QK^T (swapped): C[k][q]; A-frags contiguous-by-lane (conflict-free)
        const _Float16* ksl = &Ks[buf][lane * 8];
        f32x4 sa[4];
#pragma unroll
        for (int kg = 0; kg < 4; ++kg) {
            half8 a0 = *(const half8*)(ksl + (2 * kg + 0) * 512);
            half8 a1 = *(const half8*)(ksl + (2 * kg + 1) * 512);
            f32x4 z = zz;
            z = __builtin_amdgcn_mfma_f32_16x16x32_f16(a0, qf[0], z, 0, 0, 0);
            z = __builtin_amdgcn_mfma_f32_16x16x32_f16(a1, qf[1], z, 0, 0, 0);
            sa[kg] = z;
        }

        // ---- scores (log2 domain): s = sa + (qbf*ak + aq)*bt
        if (t == 0 && g == 0) btc[0] = 0.f;  // k=0 column has no bias
        float s[16];
#pragma unroll
        for (int kg = 0; kg < 4; ++kg) {
#pragma unroll
            for (int r = 0; r < 4; ++r) {
                const int i = kg * 4 + r;
                s[i] = fmaf(fmaf(qbf, akc[kg][r], aq), btc[i], sa[kg][r]);
            }
        }
        if (t == NQT - 1) {  // mask k >= N (only k=1024 = i0,g0 survives)
#pragma unroll
            for (int kg = 0; kg < 4; ++kg)
#pragma unroll
                for (int r = 0; r < 4; ++r) {
                    const int i = kg * 4 + r;
                    if (1024 + kg * 16 + g * 4 + r >= N_) s[i] = -1e30f;
                }
        }

        // ---- defer-max online softmax: no cross-lane work in the common path
        float lmax = s[0];
#pragma unroll
        for (int i = 1; i < 16; ++i) lmax = fmaxf(lmax, s[i]);
        if (t == 0) {
            float mt = fmaxf(lmax, __shfl_xor(lmax, 16));
            m = fmaxf(mt, __shfl_xor(mt, 32));
        } else if (!__all(lmax <= m + THR_)) {
            float mt = fmaxf(lmax, __shfl_xor(lmax, 16));
            mt = fmaxf(mt, __shfl_xor(mt, 32));
            const float mnew = fmaxf(m, mt);
            const float cc = EX2(m - mnew);
            m = mnew;
            lsum *= cc;
            float cc4[4];
#pragma unroll
            for (int r = 0; r < 4; ++r) cc4[r] = __shfl(cc, g * 4 + r);
#pragma unroll
            for (int dg = 0; dg < 4; ++dg)
#pragma unroll
                for (int r = 0; r < 4; ++r) o[dg][r] *= cc4[r];
        }
        float pv16[16];
        float ls0 = 0.f, ls1 = 0.f;
#pragma unroll
        for (int i = 0; i < 16; i += 2) {
            pv16[i] = EX2(s[i] - m);
            pv16[i + 1] = EX2(s[i + 1] - m);
            ls0 += pv16[i];
            ls1 += pv16[i + 1];
        }
        lsum += ls0 + ls1;

        // ---- P -> f16, XOR-swizzled per-wave LDS
#pragma unroll
        for (int kg = 0; kg < 4; ++kg) {
            fp16x2 h0 = __builtin_amdgcn_cvt_pkrtz(pv16[kg * 4 + 0], pv16[kg * 4 + 1]);
            fp16x2 h1 = __builtin_amdgcn_cvt_pkrtz(pv16[kg * 4 + 2], pv16[kg * 4 + 3]);
            uint2 u = make_uint2(__builtin_bit_cast(uint32_t, h0),
                                 __builtin_bit_cast(uint32_t, h1));
            *(uint2*)(plw + lq * 128 + ((kg * 32 + g * 8) ^ pswz)) = u;
        }

        // ---- PV: C[q][d] += P[q][k] V[k][d]
#pragma unroll
        for (int kh = 0; kh < 2; ++kh) {
            half8 pa = *(const half8*)(plw + lq * 128 + ((kh * 64 + g * 16) ^ pswz));
#pragma unroll
            for (int dg = 0; dg < 4; ++dg) {
                half8 vb8 = *(const half8*)&Vs[buf][(kh * 4 + dg) * 512 + lane * 8];
                o[dg] = __builtin_amdgcn_mfma_f32_16x16x32_f16(pa, vb8, o[dg], 0, 0, 0);
            }
        }
        __syncthreads();

        // ---- rotate prefetched operands into current (straight register moves)
#pragma unroll
        for (int i = 0; i < 16; ++i) btc[i] = btn[i];
#pragma unroll
        for (int kg = 0; kg < 4; ++kg) akc[kg] = akn[kg];
    }

    lsum += __shfl_xor(lsum, 16);
    lsum += __shfl_xor(lsum, 32);
    const float linv = 1.f / lsum;
    float li4[4];
#pragma unroll
    for (int r = 0; r < 4; ++r) li4[r] = __shfl(linv, g * 4 + r);
#pragma unroll
    for (int dg = 0; dg < 4; ++dg) {
#pragma unroll
        for (int r = 0; r < 4; ++r) {
            const int qq = qt * 64 + w * 16 + g * 4 + r;
            if (qq < N_) OUT[base + (size_t)qq * D_ + dg * 16 + lq] = o[dg][r] * li4[r];
        }
    }
}

extern "C" void kernel_launch(void* const* d_in, const int* in_sizes, int n_in,
                              void* d_out, int out_size, void* d_ws, size_t ws_size,
                              hipStream_t stream) {
    const float* q = (const float*)d_in[0];
    const float* k = (const float*)d_in[1];
    const float* v = (const float*)d_in[2];
    const float* mu = (const float*)d_in[3];
    const float* w1 = (const float*)d_in[4];
    const float* b1 = (const float*)d_in[5];
    const float* w2 = (const float*)d_in[6];
    const float* gamma = (const float*)d_in[7];
    const float* rel = (const float*)d_in[8];
    // d_in[9] = idx_table: reconstructed analytically, never read.

    char* ws = (char*)d_ws;
    float* akT = (float*)(ws + AKT_OFF);
    float* btR = (float*)(ws + BTR_OFF);
    _Float16* Kf = (_Float16*)(ws + KF_OFF);
    _Float16* Vf = (_Float16*)(ws + VF_OFF);

    prep<<<NBLK + (TBL_ + 255) / 256, 256, 0, stream>>>(k, v, mu, gamma, rel, w1, b1, w2,
                                                        Kf, Vf, akT, btR);
    flex_attn<<<NBLK, 256, 0, stream>>>(q, Kf, Vf, mu, gamma, ws + BTR_OFF, akT,
                                        (float*)d_out);
}

// Round 16
// 65.787 us; speedup vs baseline: 1.1687x; 1.1687x over previous
//
#include <hip/hip_runtime.h>
#include <math.h>

#define B_ 4
#define H_ 12
#define N_ 1025
#define D_ 64
#define HID_ 32
#define TBL_ 3969            // (2*32-1)^2
#define NQT 17               // 64-row tiles in both q and k
#define NBLK (B_ * H_ * NQT) // 816, divisible by 8
#define LOG2E 1.44269504f
#define THR_ 12.0f           // defer-max threshold (log2 domain); p <= 2^12 fits f16

typedef _Float16 half8 __attribute__((ext_vector_type(8)));
typedef __fp16 fp16x2 __attribute__((ext_vector_type(2)));
typedef float f32x4 __attribute__((ext_vector_type(4)));
typedef float f32x4u __attribute__((ext_vector_type(4), aligned(4)));  // 4B-aligned float4

#if defined(__has_builtin)
#if __has_builtin(__builtin_amdgcn_exp2f)
#define EX2 __builtin_amdgcn_exp2f
#else
#define EX2 exp2f
#endif
#else
#define EX2 exp2f
#endif

// ws layout (bytes):
//   akT @ 0        : 48*1088*4 = 208896   (also the pad for btR's small underrun)
//   btR @ 208896   : 12*3969*4 = 190512   (REVERSED bias table: btR[h][y]=bt[h][3968-y])
//   Kf  @ 399408   : 48*17*4096*2 = 6684672
//   Vf  @ 7084080  : 6684672              (end 13768752; tail-tile gather overruns stay in ws)
#define AKT_OFF 0
#define BTR_OFF 208896
#define KF_OFF 399408
#define VF_OFF 7084080

__device__ __forceinline__ void stage16(const _Float16* gsrc, _Float16* ldst) {
    __builtin_amdgcn_global_load_lds(
        (const __attribute__((address_space(1))) void*)gsrc,
        (__attribute__((address_space(3))) void*)ldst, 16, 0, 0);
}

// ---------------- prep: K/V -> f16 fragment-order tiles (V via LDS transpose),
// akT = sigmoid(gamma)*log2e*mu_k, btR = REVERSED MLP bias table (per-head)
__global__ __launch_bounds__(256) void prep(
    const float* __restrict__ K, const float* __restrict__ V,
    const float* __restrict__ MU, const float* __restrict__ GAMMA,
    const float* __restrict__ rel, const float* __restrict__ w1,
    const float* __restrict__ b1, const float* __restrict__ w2,
    _Float16* __restrict__ Kf, _Float16* __restrict__ Vf,
    float* __restrict__ akT, float* __restrict__ btR) {
    const int bid = blockIdx.x;
    const int tid = threadIdx.x;
    if (bid < NBLK) {
        __shared__ float Vls[64 * 65];  // [d][k], pad 65 (2-way banks max)
        const int bh = bid / NQT, kt = bid % NQT;
        const size_t base = (size_t)bh * (N_ * D_);
        const int k0 = kt * 64;
        // V rows: coalesced global read -> transposed LDS scatter
#pragma unroll
        for (int it = 0; it < 4; ++it) {
            const int idx = it * 256 + tid;
            const int kr = idx >> 4, c4 = (idx & 15) << 2;
            const int kg = k0 + kr;
            float4 v4 = make_float4(0, 0, 0, 0);
            if (kg < N_) v4 = *(const float4*)(V + base + (size_t)kg * D_ + c4);
            Vls[(c4 + 0) * 65 + kr] = v4.x;
            Vls[(c4 + 1) * 65 + kr] = v4.y;
            Vls[(c4 + 2) * 65 + kr] = v4.z;
            Vls[(c4 + 3) * 65 + kr] = v4.w;
        }
        __syncthreads();
        const int lane = tid & 63, lq = lane & 15, g = lane >> 4;
        const int fbh = tid >> 6;
        const size_t tb = (size_t)(bh * NQT + kt) * 4096;
#pragma unroll
        for (int x = 0; x < 2; ++x) {
            const int fb = fbh + x * 4;
            {   // V fragment fb = kh*4+dg from LDS
                const int kh = fb >> 2, dg = fb & 3;
                const float* vp = &Vls[(dg * 16 + lq) * 65 + kh * 32 + g * 8];
                half8 v8;
#pragma unroll
                for (int j = 0; j < 8; ++j) v8[j] = (_Float16)vp[j];
                *(half8*)&Vf[tb + fb * 512 + lane * 8] = v8;
            }
            {   // K fragment fb = kg2*2+dh, direct
                const int row = k0 + (fb >> 1) * 16 + lq;
                const int col = (fb & 1) * 32 + g * 8;
                half8 k8;
                if (row < N_) {
                    const float4* p = (const float4*)(K + base + (size_t)row * D_ + col);
                    float4 a = p[0], b = p[1];
                    k8[0] = (_Float16)a.x; k8[1] = (_Float16)a.y;
                    k8[2] = (_Float16)a.z; k8[3] = (_Float16)a.w;
                    k8[4] = (_Float16)b.x; k8[5] = (_Float16)b.y;
                    k8[6] = (_Float16)b.z; k8[7] = (_Float16)b.w;
                } else {
#pragma unroll
                    for (int j = 0; j < 8; ++j) k8[j] = (_Float16)0.f;
                }
                *(half8*)&Kf[tb + fb * 512 + lane * 8] = k8;
            }
        }
        if (tid < 64) {
            const int kk = k0 + tid;
            const int h = bh % H_;
            const float sgl = LOG2E / (1.f + __expf(-GAMMA[h]));
            float a = 0.f;
            if (kk >= 1 && kk < N_) a = sgl * MU[((size_t)bh * 2 + 1) * N_ + kk];
            akT[bh * 1088 + kk] = a;
        }
    } else {
        const int i = (bid - NBLK) * 256 + tid;
        if (i < TBL_) {
            const float x0 = rel[2 * i + 0], x1 = rel[2 * i + 1];
            float acc[H_];
#pragma unroll
            for (int h = 0; h < H_; ++h) acc[h] = 0.f;
#pragma unroll
            for (int j = 0; j < HID_; ++j) {
                float t = fmaf(x0, w1[j], fmaf(x1, w1[HID_ + j], b1[j]));
                float gl = 0.5f * t * (1.f + erff(t * 0.7071067811865475f));  // exact gelu
#pragma unroll
                for (int h = 0; h < H_; ++h) acc[h] = fmaf(gl, w2[j * H_ + h], acc[h]);
            }
#pragma unroll
            for (int h = 0; h < H_; ++h) btR[h * TBL_ + (TBL_ - 1 - i)] = acc[h];
        }
    }
}

// inlined, spill-free bias gather (constant-indexed array writes only)
#define GATHER_BIAS(BT)                                                          \
    {                                                                            \
        _Pragma("unroll") for (int kg = 0; kg < 4; ++kg) {                       \
            const int off = boff4[kg];                                           \
            if (kg & 1) { /* never crosses a 32-row boundary */                  \
                f32x4u f4 = *(const f32x4u*)(btb + off);                         \
                BT[kg * 4 + 0] = f4[0]; BT[kg * 4 + 1] = f4[1];                  \
                BT[kg * 4 + 2] = f4[2]; BT[kg * 4 + 3] = f4[3];                  \
            } else { /* g==0 lanes cross: r0 separate, r1..r3 at +32 elems */    \
                const bool cross = (g == 0);                                     \
                f32x4u f4 = *(const f32x4u*)(btb + off + (cross ? 128 : 0));     \
                const float s0v = *(const float*)(btb + off);                    \
                BT[kg * 4 + 0] = s0v;                                            \
                BT[kg * 4 + 1] = cross ? f4[0] : f4[1];                          \
                BT[kg * 4 + 2] = cross ? f4[1] : f4[2];                          \
                BT[kg * 4 + 3] = cross ? f4[2] : f4[3];                          \
            }                                                                    \
            boff4[kg] += 504;                                                    \
        }                                                                        \
    }

// ---------------- fused flash attention, f16 MFMA, DMA-staged fragment tiles
// (round-12 structure) + one-tile-ahead bias/ak prefetch.
// NOTE: launch_bounds (256,3): the (256,4) builds empirically cap VGPR at 64,
// which forced the prefetch state into scratch (r14/r15: +27MB HBM spill).
// LDS (40KB) still caps residency at 4 blocks/CU, so occupancy is unchanged.
__global__ __launch_bounds__(256, 3) void flex_attn(
    const float* __restrict__ Q, const _Float16* __restrict__ Kf,
    const _Float16* __restrict__ Vf, const float* __restrict__ MU,
    const float* __restrict__ GAMMA, const char* __restrict__ btb,  // = ws + BTR_OFF
    const float* __restrict__ akT, float* __restrict__ OUT) {
    __shared__ __align__(16) _Float16 Ks[2][4096];
    __shared__ __align__(16) _Float16 Vs[2][4096];
    __shared__ __align__(16) _Float16 Pl[4][1024];  // [wave][16 q][64 k] XOR-swizzled

    const int bid = blockIdx.x;
    const int swz0 = (bid & 7) * (NBLK / 8) + (bid >> 3);  // bijective XCD swizzle
    const int bh = swz0 / NQT;
    const int qt = swz0 % NQT;
    const int h = bh % H_;
    const int tid = threadIdx.x;
    const int w = tid >> 6;
    const int lane = tid & 63;
    const int lq = lane & 15;
    const int g = lane >> 4;

    const size_t base = (size_t)bh * (N_ * D_);
    const float sg = LOG2E / (1.f + __expf(-GAMMA[h]));

    const int qrow = qt * 64 + w * 16 + lq;
    const bool qv = qrow < N_;

    // Q fragment (B-operand of swapped QK^T), scale = log2e/sqrt(64)
    half8 qf[2];
#pragma unroll
    for (int dh = 0; dh < 2; ++dh) {
        float4 t0 = make_float4(0, 0, 0, 0), t1 = t0;
        if (qv) {
            const float4* qp = (const float4*)(Q + base + (size_t)qrow * D_ + dh * 32 + g * 8);
            t0 = qp[0]; t1 = qp[1];
        }
        const float qs = 0.125f * LOG2E;
        half8 q8;
        q8[0] = (_Float16)(t0.x * qs); q8[1] = (_Float16)(t0.y * qs);
        q8[2] = (_Float16)(t0.z * qs); q8[3] = (_Float16)(t0.w * qs);
        q8[4] = (_Float16)(t1.x * qs); q8[5] = (_Float16)(t1.y * qs);
        q8[6] = (_Float16)(t1.z * qs); q8[7] = (_Float16)(t1.w * qs);
        qf[dh] = q8;
    }

    const bool qb = qv && (qrow >= 1);
    const float qbf = qb ? 1.f : 0.f;
    float aq = 0.f;
    int cq = 0;
    if (qb) {
        const int pq = qrow - 1;
        cq = (pq >> 5) * 63 + (pq & 31);
        aq = sg * MU[(size_t)bh * 2 * N_ + qrow];  // sg*log2e*mu_q
    }
    // REVERSED table: value(ck) = btR[h*TBL + 1984 - cq + ck] -> forward-consecutive
    // in ck. Quads consecutive except (kg even && g==0): r0 separate, r1..3 at +32.
    // Per-tile recurrence: ck += 126 -> byte offset += 504.
    int boff4[4];
#pragma unroll
    for (int kg = 0; kg < 4; ++kg) {
        const int pk0 = kg * 16 + g * 4 - 1;              // tile 0
        const int ck0 = (pk0 >> 5) * 63 + (pk0 & 31);     // arith shift: ck0(-1) = -32
        boff4[kg] = (h * TBL_ + 1984 - cq + ck0) * 4;
    }
    const float* akb = akT + bh * 1088;
    const _Float16* kfb = Kf + (size_t)bh * NQT * 4096;
    const _Float16* vfb = Vf + (size_t)bh * NQT * 4096;

    f32x4 o[4];
    const f32x4 zz = {0.f, 0.f, 0.f, 0.f};
#pragma unroll
    for (int dg = 0; dg < 4; ++dg) o[dg] = zz;
    float m = 0.f, lsum = 0.f;

    // prologue: stage tile 0 into buf 0; gather tile 0's bias/ak into current regs
    stage16(kfb + (2 * w + 0) * 512 + lane * 8, &Ks[0][(2 * w + 0) * 512]);
    stage16(kfb + (2 * w + 1) * 512 + lane * 8, &Ks[0][(2 * w + 1) * 512]);
    stage16(vfb + (2 * w + 0) * 512 + lane * 8, &Vs[0][(2 * w + 0) * 512]);
    stage16(vfb + (2 * w + 1) * 512 + lane * 8, &Vs[0][(2 * w + 1) * 512]);
    float btc[16];
    GATHER_BIAS(btc)
    f32x4 akc[4];
#pragma unroll
    for (int kg = 0; kg < 4; ++kg) akc[kg] = *(const f32x4*)(akb + kg * 16 + g * 4);
    __syncthreads();

    const int pswz = (lq & 7) << 4;
    char* plw = (char*)&Pl[w][0];

    for (int t = 0; t < NQT; ++t) {
        const int buf = t & 1;

        // ---- stage next tile into the other buffer
        if (t + 1 < NQT) {
            const _Float16* kn = kfb + (size_t)(t + 1) * 4096;
            const _Float16* vn = vfb + (size_t)(t + 1) * 4096;
            stage16(kn + (2 * w + 0) * 512 + lane * 8, &Ks[buf ^ 1][(2 * w + 0) * 512]);
            stage16(kn + (2 * w + 1) * 512 + lane * 8, &Ks[buf ^ 1][(2 * w + 1) * 512]);
            stage16(vn + (2 * w + 0) * 512 + lane * 8, &Vs[buf ^ 1][(2 * w + 0) * 512]);
            stage16(vn + (2 * w + 1) * 512 + lane * 8, &Vs[buf ^ 1][(2 * w + 1) * 512]);
        }

        // ---- prefetch NEXT tile's bias/ak (consumed next iteration, after the
        //      barrier's vmcnt drain -> zero exposed latency at use)
        float btn[16];
        GATHER_BIAS(btn)
        f32x4 akn[4];
        {
            const int kt1 = (t + 1 < NQT) ? (t + 1) * 64 : t * 64;
#pragma unroll
            for (int kg = 0; kg < 4; ++kg)
                akn[kg] = *(const f32x4*)(akb + kt1 + kg * 16 + g * 4);
        }

        // ---- QK^T (swapped): C[k][q]; A-frags contiguous-by-lane (conflict-free)
        const _Float16* ksl = &Ks[buf][lane * 8];
        f32x4 sa[4];
#pragma unroll
        for (int kg = 0; kg < 4; ++kg) {
            half8 a0 = *(const half8*)(ksl + (2 * kg + 0) * 512);
            half8 a1 = *(const half8*)(ksl + (2 * kg + 1) * 512);
            f32x4 z = zz;
            z = __builtin_amdgcn_mfma_f32_16x16x32_f16(a0, qf[0], z, 0, 0, 0);
            z = __builtin_amdgcn_mfma_f32_16x16x32_f16(a1, qf[1], z, 0, 0, 0);
            sa[kg] = z;
        }

        // ---- scores (log2 domain): s = sa + (qbf*ak + aq)*bt
        if (t == 0 && g == 0) btc[0] = 0.f;  // k=0 column has no bias
        float s[16];
#pragma unroll
        for (int kg = 0; kg < 4; ++kg) {
#pragma unroll
            for (int r = 0; r < 4; ++r) {
                const int i = kg * 4 + r;
                s[i] = fmaf(fmaf(qbf, akc[kg][r], aq), btc[i], sa[kg][r]);
            }
        }
        if (t == NQT - 1) {  // mask k >= N (only k=1024 = i0,g0 survives)
#pragma unroll
            for (int kg = 0; kg < 4; ++kg)
#pragma unroll
                for (int r = 0; r < 4; ++r) {
                    const int i = kg * 4 + r;
                    if (1024 + kg * 16 + g * 4 + r >= N_) s[i] = -1e30f;
                }
        }

        // ---- defer-max online softmax: no cross-lane work in the common path
        float lmax = s[0];
#pragma unroll
        for (int i = 1; i < 16; ++i) lmax = fmaxf(lmax, s[i]);
        if (t == 0) {
            float mt = fmaxf(lmax, __shfl_xor(lmax, 16));
            m = fmaxf(mt, __shfl_xor(mt, 32));
        } else if (!__all(lmax <= m + THR_)) {
            float mt = fmaxf(lmax, __shfl_xor(lmax, 16));
            mt = fmaxf(mt, __shfl_xor(mt, 32));
            const float mnew = fmaxf(m, mt);
            const float cc = EX2(m - mnew);
            m = mnew;
            lsum *= cc;
            float cc4[4];
#pragma unroll
            for (int r = 0; r < 4; ++r) cc4[r] = __shfl(cc, g * 4 + r);
#pragma unroll
            for (int dg = 0; dg < 4; ++dg)
#pragma unroll
                for (int r = 0; r < 4; ++r) o[dg][r] *= cc4[r];
        }
        float pv16[16];
        float ls0 = 0.f, ls1 = 0.f;
#pragma unroll
        for (int i = 0; i < 16; i += 2) {
            pv16[i] = EX2(s[i] - m);
            pv16[i + 1] = EX2(s[i + 1] - m);
            ls0 += pv16[i];
            ls1 += pv16[i + 1];
        }
        lsum += ls0 + ls1;

        // ---- P -> f16, XOR-swizzled per-wave LDS
#pragma unroll
        for (int kg = 0; kg < 4; ++kg) {
            fp16x2 h0 = __builtin_amdgcn_cvt_pkrtz(pv16[kg * 4 + 0], pv16[kg * 4 + 1]);
            fp16x2 h1 = __builtin_amdgcn_cvt_pkrtz(pv16[kg * 4 + 2], pv16[kg * 4 + 3]);
            uint2 u = make_uint2(__builtin_bit_cast(uint32_t, h0),
                                 __builtin_bit_cast(uint32_t, h1));
            *(uint2*)(plw + lq * 128 + ((kg * 32 + g * 8) ^ pswz)) = u;
        }

        // ---- PV: C[q][d] += P[q][k] V[k][d]
#pragma unroll
        for (int kh = 0; kh < 2; ++kh) {
            half8 pa = *(const half8*)(plw + lq * 128 + ((kh * 64 + g * 16) ^ pswz));
#pragma unroll
            for (int dg = 0; dg < 4; ++dg) {
                half8 vb8 = *(const half8*)&Vs[buf][(kh * 4 + dg) * 512 + lane * 8];
                o[dg] = __builtin_amdgcn_mfma_f32_16x16x32_f16(pa, vb8, o[dg], 0, 0, 0);
            }
        }
        __syncthreads();

        // ---- rotate prefetched operands into current (straight register moves)
#pragma unroll
        for (int i = 0; i < 16; ++i) btc[i] = btn[i];
#pragma unroll
        for (int kg = 0; kg < 4; ++kg) akc[kg] = akn[kg];
    }

    lsum += __shfl_xor(lsum, 16);
    lsum += __shfl_xor(lsum, 32);
    const float linv = 1.f / lsum;
    float li4[4];
#pragma unroll
    for (int r = 0; r < 4; ++r) li4[r] = __shfl(linv, g * 4 + r);
#pragma unroll
    for (int dg = 0; dg < 4; ++dg) {
#pragma unroll
        for (int r = 0; r < 4; ++r) {
            const int qq = qt * 64 + w * 16 + g * 4 + r;
            if (qq < N_) OUT[base + (size_t)qq * D_ + dg * 16 + lq] = o[dg][r] * li4[r];
        }
    }
}

extern "C" void kernel_launch(void* const* d_in, const int* in_sizes, int n_in,
                              void* d_out, int out_size, void* d_ws, size_t ws_size,
                              hipStream_t stream) {
    const float* q = (const float*)d_in[0];
    const float* k = (const float*)d_in[1];
    const float* v = (const float*)d_in[2];
    const float* mu = (const float*)d_in[3];
    const float* w1 = (const float*)d_in[4];
    const float* b1 = (const float*)d_in[5];
    const float* w2 = (const float*)d_in[6];
    const float* gamma = (const float*)d_in[7];
    const float* rel = (const float*)d_in[8];
    // d_in[9] = idx_table: reconstructed analytically, never read.

    char* ws = (char*)d_ws;
    float* akT = (float*)(ws + AKT_OFF);
    float* btR = (float*)(ws + BTR_OFF);
    _Float16* Kf = (_Float16*)(ws + KF_OFF);
    _Float16* Vf = (_Float16*)(ws + VF_OFF);

    prep<<<NBLK + (TBL_ + 255) / 256, 256, 0, stream>>>(k, v, mu, gamma, rel, w1, b1, w2,
                                                        Kf, Vf, akT, btR);
    flex_attn<<<NBLK, 256, 0, stream>>>(q, Kf, Vf, mu, gamma, ws + BTR_OFF, akT,
                                        (float*)d_out);
}

// Round 17
// 64.224 us; speedup vs baseline: 1.1971x; 1.0243x over previous
//
#include <hip/hip_runtime.h>
#include <math.h>

#define B_ 4
#define H_ 12
#define N_ 1025
#define D_ 64
#define HID_ 32
#define TBL_ 3969            // (2*32-1)^2
#define NQT 17               // 64-row tiles in both q and k
#define NBLK (B_ * H_ * NQT) // 816, divisible by 8
#define NKB 1632             // K-reorder streaming blocks: 48*17*512 threads / 256
#define LOG2E 1.44269504f
#define THR_ 12.0f           // defer-max threshold (log2 domain); p <= 2^12 fits f16

typedef _Float16 half8 __attribute__((ext_vector_type(8)));
typedef __fp16 fp16x2 __attribute__((ext_vector_type(2)));
typedef float f32x4 __attribute__((ext_vector_type(4)));
typedef float f32x4u __attribute__((ext_vector_type(4), aligned(4)));  // 4B-aligned float4

#if defined(__has_builtin)
#if __has_builtin(__builtin_amdgcn_exp2f)
#define EX2 __builtin_amdgcn_exp2f
#else
#define EX2 exp2f
#endif
#else
#define EX2 exp2f
#endif

// ws layout (bytes):
//   akT @ 0        : 48*1088*4 = 208896   (also the pad for btR's small underrun)
//   btR @ 208896   : 12*3969*4 = 190512   (REVERSED bias table: btR[h][y]=bt[h][3968-y])
//   Kf  @ 399408   : 48*17*4096*2 = 6684672
//   Vf  @ 7084080  : 6684672              (end 13768752; tail-tile gather overruns stay in ws)
#define AKT_OFF 0
#define BTR_OFF 208896
#define KF_OFF 399408
#define VF_OFF 7084080

__device__ __forceinline__ void stage16(const _Float16* gsrc, _Float16* ldst) {
    __builtin_amdgcn_global_load_lds(
        (const __attribute__((address_space(1))) void*)gsrc,
        (__attribute__((address_space(3))) void*)ldst, 16, 0, 0);
}

// ---------------- prep, role-split blocks:
//   [0, NBLK)            V-transpose tiles (LDS) + akT
//   [NBLK, NBLK+NKB)     K reorder: pure streaming, no LDS, no barrier
//   [NBLK+NKB, ...)      bias-table MLP (reversed table)
__global__ __launch_bounds__(256) void prep(
    const float* __restrict__ K, const float* __restrict__ V,
    const float* __restrict__ MU, const float* __restrict__ GAMMA,
    const float* __restrict__ rel, const float* __restrict__ w1,
    const float* __restrict__ b1, const float* __restrict__ w2,
    _Float16* __restrict__ Kf, _Float16* __restrict__ Vf,
    float* __restrict__ akT, float* __restrict__ btR) {
    const int bid = blockIdx.x;
    const int tid = threadIdx.x;
    if (bid < NBLK) {
        // ---- V tile: coalesced row read -> f32 LDS transpose (pad 65) -> frags
        __shared__ float Vls[64 * 65];
        const int bh = bid / NQT, kt = bid % NQT;
        const size_t base = (size_t)bh * (N_ * D_);
        const int k0 = kt * 64;
#pragma unroll
        for (int it = 0; it < 4; ++it) {
            const int idx = it * 256 + tid;
            const int kr = idx >> 4, c4 = (idx & 15) << 2;
            const int kg = k0 + kr;
            float4 v4 = make_float4(0, 0, 0, 0);
            if (kg < N_) v4 = *(const float4*)(V + base + (size_t)kg * D_ + c4);
            Vls[(c4 + 0) * 65 + kr] = v4.x;
            Vls[(c4 + 1) * 65 + kr] = v4.y;
            Vls[(c4 + 2) * 65 + kr] = v4.z;
            Vls[(c4 + 3) * 65 + kr] = v4.w;
        }
        if (tid < 64) {
            const int kk = k0 + tid;
            const int h = bh % H_;
            const float sgl = LOG2E / (1.f + __expf(-GAMMA[h]));
            float a = 0.f;
            if (kk >= 1 && kk < N_) a = sgl * MU[((size_t)bh * 2 + 1) * N_ + kk];
            akT[bh * 1088 + kk] = a;
        }
        __syncthreads();
        const int lane = tid & 63, lq = lane & 15, g = lane >> 4;
        const int fbh = tid >> 6;
        const size_t tb = (size_t)(bh * NQT + kt) * 4096;
#pragma unroll
        for (int x = 0; x < 2; ++x) {
            const int fb = fbh + x * 4;  // V fragment fb = kh*4+dg
            const int kh = fb >> 2, dg = fb & 3;
            const float* vp = &Vls[(dg * 16 + lq) * 65 + kh * 32 + g * 8];
            half8 v8;
#pragma unroll
            for (int j = 0; j < 8; ++j) v8[j] = (_Float16)vp[j];
            *(half8*)&Vf[tb + fb * 512 + lane * 8] = v8;
        }
    } else if (bid < NBLK + NKB) {
        // ---- K reorder: one fragment-half8 per thread, pure streaming
        const int gt = (bid - NBLK) * 256 + tid;   // 0 .. 48*17*512-1
        const int lane = gt & 63;
        const int fb = (gt >> 6) & 7;
        const int kt = (gt >> 9) % NQT;
        const int bh = gt / (NQT * 512);
        const int lq = lane & 15, g = lane >> 4;
        const size_t base = (size_t)bh * (N_ * D_);
        const int row = kt * 64 + (fb >> 1) * 16 + lq;
        const int col = (fb & 1) * 32 + g * 8;
        half8 k8;
        if (row < N_) {
            const float4* p = (const float4*)(K + base + (size_t)row * D_ + col);
            float4 a = p[0], b = p[1];
            k8[0] = (_Float16)a.x; k8[1] = (_Float16)a.y;
            k8[2] = (_Float16)a.z; k8[3] = (_Float16)a.w;
            k8[4] = (_Float16)b.x; k8[5] = (_Float16)b.y;
            k8[6] = (_Float16)b.z; k8[7] = (_Float16)b.w;
        } else {
#pragma unroll
            for (int j = 0; j < 8; ++j) k8[j] = (_Float16)0.f;
        }
        *(half8*)&Kf[((size_t)(bh * NQT + kt) * 8 + fb) * 512 + lane * 8] = k8;
    } else {
        const int i = (bid - NBLK - NKB) * 256 + tid;
        if (i < TBL_) {
            const float x0 = rel[2 * i + 0], x1 = rel[2 * i + 1];
            float acc[H_];
#pragma unroll
            for (int h = 0; h < H_; ++h) acc[h] = 0.f;
#pragma unroll
            for (int j = 0; j < HID_; ++j) {
                float t = fmaf(x0, w1[j], fmaf(x1, w1[HID_ + j], b1[j]));
                float gl = 0.5f * t * (1.f + erff(t * 0.7071067811865475f));  // exact gelu
#pragma unroll
                for (int h = 0; h < H_; ++h) acc[h] = fmaf(gl, w2[j * H_ + h], acc[h]);
            }
#pragma unroll
            for (int h = 0; h < H_; ++h) btR[h * TBL_ + (TBL_ - 1 - i)] = acc[h];
        }
    }
}

// ---------------- fused flash attention, f16 MFMA, DMA-staged fragment tiles
// (round-12 structure, byte-exact) + quad-vectorized bias gathers (reversed table)
__global__ __launch_bounds__(256, 4) void flex_attn(
    const float* __restrict__ Q, const _Float16* __restrict__ Kf,
    const _Float16* __restrict__ Vf, const float* __restrict__ MU,
    const float* __restrict__ GAMMA, const char* __restrict__ btb,  // = ws + BTR_OFF
    const float* __restrict__ akT, float* __restrict__ OUT) {
    __shared__ __align__(16) _Float16 Ks[2][4096];
    __shared__ __align__(16) _Float16 Vs[2][4096];
    __shared__ __align__(16) _Float16 Pl[4][1024];  // [wave][16 q][64 k] XOR-swizzled

    const int bid = blockIdx.x;
    const int swz0 = (bid & 7) * (NBLK / 8) + (bid >> 3);  // bijective XCD swizzle
    const int bh = swz0 / NQT;
    const int qt = swz0 % NQT;
    const int h = bh % H_;
    const int tid = threadIdx.x;
    const int w = tid >> 6;
    const int lane = tid & 63;
    const int lq = lane & 15;
    const int g = lane >> 4;

    const size_t base = (size_t)bh * (N_ * D_);
    const float sg = LOG2E / (1.f + __expf(-GAMMA[h]));

    const int qrow = qt * 64 + w * 16 + lq;
    const bool qv = qrow < N_;

    // Q fragment (B-operand of swapped QK^T), scale = log2e/sqrt(64)
    half8 qf[2];
#pragma unroll
    for (int dh = 0; dh < 2; ++dh) {
        float4 t0 = make_float4(0, 0, 0, 0), t1 = t0;
        if (qv) {
            const float4* qp = (const float4*)(Q + base + (size_t)qrow * D_ + dh * 32 + g * 8);
            t0 = qp[0]; t1 = qp[1];
        }
        const float qs = 0.125f * LOG2E;
        half8 q8;
        q8[0] = (_Float16)(t0.x * qs); q8[1] = (_Float16)(t0.y * qs);
        q8[2] = (_Float16)(t0.z * qs); q8[3] = (_Float16)(t0.w * qs);
        q8[4] = (_Float16)(t1.x * qs); q8[5] = (_Float16)(t1.y * qs);
        q8[6] = (_Float16)(t1.z * qs); q8[7] = (_Float16)(t1.w * qs);
        qf[dh] = q8;
    }

    const bool qb = qv && (qrow >= 1);
    const float qbf = qb ? 1.f : 0.f;
    float aq = 0.f;
    int cq = 0;
    if (qb) {
        const int pq = qrow - 1;
        cq = (pq >> 5) * 63 + (pq & 31);
        aq = sg * MU[(size_t)bh * 2 * N_ + qrow];  // sg*log2e*mu_q
    }
    // REVERSED table: value(ck) = btR[h*TBL + 1984 - cq + ck] -> forward-consecutive
    // in ck. Per-kg quad r=0..3 has ck consecutive except the quads starting at
    // pk0 % 32 == 31 (exactly g==0 && kg even): there ck(r1) = ck(r0)+32.
    // Per-tile recurrence: ck += 126 -> byte offset += 504.
    int boff4[4];
#pragma unroll
    for (int kg = 0; kg < 4; ++kg) {
        const int pk0 = kg * 16 + g * 4 - 1;              // tile 0
        const int ck0 = (pk0 >> 5) * 63 + (pk0 & 31);     // arith shift: ck0(-1) = -32
        boff4[kg] = (h * TBL_ + 1984 - cq + ck0) * 4;
    }
    const float* akb = akT + bh * 1088;
    const _Float16* kfb = Kf + (size_t)bh * NQT * 4096;
    const _Float16* vfb = Vf + (size_t)bh * NQT * 4096;

    f32x4 o[4];
    const f32x4 zz = {0.f, 0.f, 0.f, 0.f};
#pragma unroll
    for (int dg = 0; dg < 4; ++dg) o[dg] = zz;
    float m = 0.f, lsum = 0.f;

    // prologue: stage tile 0 into buf 0
    stage16(kfb + (2 * w + 0) * 512 + lane * 8, &Ks[0][(2 * w + 0) * 512]);
    stage16(kfb + (2 * w + 1) * 512 + lane * 8, &Ks[0][(2 * w + 1) * 512]);
    stage16(vfb + (2 * w + 0) * 512 + lane * 8, &Vs[0][(2 * w + 0) * 512]);
    stage16(vfb + (2 * w + 1) * 512 + lane * 8, &Vs[0][(2 * w + 1) * 512]);
    __syncthreads();

    const int pswz = (lq & 7) << 4;
    char* plw = (char*)&Pl[w][0];

    for (int t = 0; t < NQT; ++t) {
        const int buf = t & 1;
        const int kt0 = t * 64;

        // ---- bias gathers: 1 float4 (+1 dword for crossing quads) per kg
        float bt16[16];
#pragma unroll
        for (int kg = 0; kg < 4; ++kg) {
            const int off = boff4[kg];
            if (kg & 1) {  // never crosses a 32-row boundary
                f32x4u f4 = *(const f32x4u*)(btb + off);
                bt16[kg * 4 + 0] = f4[0];
                bt16[kg * 4 + 1] = f4[1];
                bt16[kg * 4 + 2] = f4[2];
                bt16[kg * 4 + 3] = f4[3];
            } else {       // g==0 lanes cross: r0 separate, r1..r3 at +32 elements
                const bool cross = (g == 0);
                f32x4u f4 = *(const f32x4u*)(btb + off + (cross ? 128 : 0));
                const float s0v = *(const float*)(btb + off);
                bt16[kg * 4 + 0] = s0v;
                bt16[kg * 4 + 1] = cross ? f4[0] : f4[1];
                bt16[kg * 4 + 2] = cross ? f4[1] : f4[2];
                bt16[kg * 4 + 3] = cross ? f4[2] : f4[3];
            }
            boff4[kg] += 504;
        }
        // ---- gate k-terms (vectorized, r-consecutive)
        f32x4 akq[4];
#pragma unroll
        for (int kg = 0; kg < 4; ++kg)
            akq[kg] = *(const f32x4*)(akb + kt0 + kg * 16 + g * 4);

        // ---- stage next tile into the other buffer
        if (t + 1 < NQT) {
            const _Float16* kn = kfb + (size_t)(t + 1) * 4096;
            const _Float16* vn = vfb + (size_t)(t + 1) * 4096;
            stage16(kn + (2 * w + 0) * 512 + lane * 8, &Ks[buf ^ 1][(2 * w + 0) * 512]);
            stage16(kn + (2 * w + 1) * 512 + lane * 8, &Ks[buf ^ 1][(2 * w + 1) * 512]);
            stage16(vn + (2 * w + 0) * 512 + lane * 8, &Vs[buf ^ 1][(2 * w + 0) * 512]);
            stage16(vn + (2 * w + 1) * 512 + lane * 8, &Vs[buf ^ 1][(2 * w + 1) * 512]);
        }

        // ---- QK^T (swapped): C[k][q]; A-frags contiguous-by-lane (conflict-free)
        const _Float16* ksl = &Ks[buf][lane * 8];
        f32x4 sa[4];
#pragma unroll
        for (int kg = 0; kg < 4; ++kg) {
            half8 a0 = *(const half8*)(ksl + (2 * kg + 0) * 512);
            half8 a1 = *(const half8*)(ksl + (2 * kg + 1) * 512);
            f32x4 z = zz;
            z = __builtin_amdgcn_mfma_f32_16x16x32_f16(a0, qf[0], z, 0, 0, 0);
            z = __builtin_amdgcn_mfma_f32_16x16x32_f16(a1, qf[1], z, 0, 0, 0);
            sa[kg] = z;
        }

        // ---- scores (log2 domain): s = sa + (qbf*ak + aq)*bt
        if (t == 0 && g == 0) bt16[0] = 0.f;  // k=0 column has no bias
        float s[16];
#pragma unroll
        for (int kg = 0; kg < 4; ++kg) {
#pragma unroll
            for (int r = 0; r < 4; ++r) {
                const int i = kg * 4 + r;
                s[i] = fmaf(fmaf(qbf, akq[kg][r], aq), bt16[i], sa[kg][r]);
            }
        }
        if (t == NQT - 1) {  // mask k >= N (only k=1024 = i0,g0 survives)
#pragma unroll
            for (int kg = 0; kg < 4; ++kg)
#pragma unroll
                for (int r = 0; r < 4; ++r) {
                    const int i = kg * 4 + r;
                    if (1024 + kg * 16 + g * 4 + r >= N_) s[i] = -1e30f;
                }
        }

        // ---- defer-max online softmax: no cross-lane work in the common path
        float lmax = s[0];
#pragma unroll
        for (int i = 1; i < 16; ++i) lmax = fmaxf(lmax, s[i]);
        if (t == 0) {
            float mt = fmaxf(lmax, __shfl_xor(lmax, 16));
            m = fmaxf(mt, __shfl_xor(mt, 32));
        } else if (!__all(lmax <= m + THR_)) {
            float mt = fmaxf(lmax, __shfl_xor(lmax, 16));
            mt = fmaxf(mt, __shfl_xor(mt, 32));
            const float mnew = fmaxf(m, mt);
            const float cc = EX2(m - mnew);
            m = mnew;
            lsum *= cc;
            float cc4[4];
#pragma unroll
            for (int r = 0; r < 4; ++r) cc4[r] = __shfl(cc, g * 4 + r);
#pragma unroll
            for (int dg = 0; dg < 4; ++dg)
#pragma unroll
                for (int r = 0; r < 4; ++r) o[dg][r] *= cc4[r];
        }
        float pv16[16];
        float ls0 = 0.f, ls1 = 0.f;
#pragma unroll
        for (int i = 0; i < 16; i += 2) {
            pv16[i] = EX2(s[i] - m);
            pv16[i + 1] = EX2(s[i + 1] - m);
            ls0 += pv16[i];
            ls1 += pv16[i + 1];
        }
        lsum += ls0 + ls1;

        // ---- P -> f16, XOR-swizzled per-wave LDS
#pragma unroll
        for (int kg = 0; kg < 4; ++kg) {
            fp16x2 h0 = __builtin_amdgcn_cvt_pkrtz(pv16[kg * 4 + 0], pv16[kg * 4 + 1]);
            fp16x2 h1 = __builtin_amdgcn_cvt_pkrtz(pv16[kg * 4 + 2], pv16[kg * 4 + 3]);
            uint2 u = make_uint2(__builtin_bit_cast(uint32_t, h0),
                                 __builtin_bit_cast(uint32_t, h1));
            *(uint2*)(plw + lq * 128 + ((kg * 32 + g * 8) ^ pswz)) = u;
        }

        // ---- PV: C[q][d] += P[q][k] V[k][d]
#pragma unroll
        for (int kh = 0; kh < 2; ++kh) {
            half8 pa = *(const half8*)(plw + lq * 128 + ((kh * 64 + g * 16) ^ pswz));
#pragma unroll
            for (int dg = 0; dg < 4; ++dg) {
                half8 vb8 = *(const half8*)&Vs[buf][(kh * 4 + dg) * 512 + lane * 8];
                o[dg] = __builtin_amdgcn_mfma_f32_16x16x32_f16(pa, vb8, o[dg], 0, 0, 0);
            }
        }
        __syncthreads();
    }

    lsum += __shfl_xor(lsum, 16);
    lsum += __shfl_xor(lsum, 32);
    const float linv = 1.f / lsum;
    float li4[4];
#pragma unroll
    for (int r = 0; r < 4; ++r) li4[r] = __shfl(linv, g * 4 + r);
#pragma unroll
    for (int dg = 0; dg < 4; ++dg) {
#pragma unroll
        for (int r = 0; r < 4; ++r) {
            const int qq = qt * 64 + w * 16 + g * 4 + r;
            if (qq < N_) OUT[base + (size_t)qq * D_ + dg * 16 + lq] = o[dg][r] * li4[r];
        }
    }
}

extern "C" void kernel_launch(void* const* d_in, const int* in_sizes, int n_in,
                              void* d_out, int out_size, void* d_ws, size_t ws_size,
                              hipStream_t stream) {
    const float* q = (const float*)d_in[0];
    const float* k = (const float*)d_in[1];
    const float* v = (const float*)d_in[2];
    const float* mu = (const float*)d_in[3];
    const float* w1 = (const float*)d_in[4];
    const float* b1 = (const float*)d_in[5];
    const float* w2 = (const float*)d_in[6];
    const float* gamma = (const float*)d_in[7];
    const float* rel = (const float*)d_in[8];
    // d_in[9] = idx_table: reconstructed analytically, never read.

    char* ws = (char*)d_ws;
    float* akT = (float*)(ws + AKT_OFF);
    float* btR = (float*)(ws + BTR_OFF);
    _Float16* Kf = (_Float16*)(ws + KF_OFF);
    _Float16* Vf = (_Float16*)(ws + VF_OFF);

    const int prep_blocks = NBLK + NKB + (TBL_ + 255) / 256;  // 816 + 1632 + 16
    prep<<<prep_blocks, 256, 0, stream>>>(k, v, mu, gamma, rel, w1, b1, w2,
                                          Kf, Vf, akT, btR);
    flex_attn<<<NBLK, 256, 0, stream>>>(q, Kf, Vf, mu, gamma, ws + BTR_OFF, akT,
                                        (float*)d_out);
}

// Round 18
// 60.413 us; speedup vs baseline: 1.2727x; 1.0631x over previous
//
#include <hip/hip_runtime.h>
#include <math.h>

#define B_ 4
#define H_ 12
#define N_ 1025
#define D_ 64
#define HID_ 32
#define TBL_ 3969            // (2*32-1)^2
#define NQT 17               // 64-row tiles in both q and k
#define NBLK (B_ * H_ * NQT) // 816, divisible by 8
#define LOG2E 1.44269504f
#define THR_ 12.0f           // defer-max threshold (log2 domain); p <= 2^12 fits f16

typedef _Float16 half8 __attribute__((ext_vector_type(8)));
typedef __fp16 fp16x2 __attribute__((ext_vector_type(2)));
typedef float f32x4 __attribute__((ext_vector_type(4)));
typedef float f32x4u __attribute__((ext_vector_type(4), aligned(4)));  // 4B-aligned float4

#if defined(__has_builtin)
#if __has_builtin(__builtin_amdgcn_exp2f)
#define EX2 __builtin_amdgcn_exp2f
#else
#define EX2 exp2f
#endif
#else
#define EX2 exp2f
#endif

// ws layout (bytes):
//   akT @ 0        : 48*1088*4 = 208896   (also the pad for btR's small underrun)
//   btR @ 208896   : 12*3969*4 = 190512   (REVERSED bias table: btR[h][y]=bt[h][3968-y])
//   Kf  @ 399408   : 48*17*4096*2 = 6684672
//   Vf  @ 7084080  : 6684672              (end 13768752; tail-tile gather overruns stay in ws)
#define AKT_OFF 0
#define BTR_OFF 208896
#define KF_OFF 399408
#define VF_OFF 7084080

__device__ __forceinline__ void stage16(const _Float16* gsrc, _Float16* ldst) {
    __builtin_amdgcn_global_load_lds(
        (const __attribute__((address_space(1))) void*)gsrc,
        (__attribute__((address_space(3))) void*)ldst, 16, 0, 0);
}

// ---------------- prep: K/V -> f16 fragment-order tiles, both staged through LDS
// so ALL global reads are coalesced row reads. akT, btR (reversed) as before.
__global__ __launch_bounds__(256) void prep(
    const float* __restrict__ K, const float* __restrict__ V,
    const float* __restrict__ MU, const float* __restrict__ GAMMA,
    const float* __restrict__ rel, const float* __restrict__ w1,
    const float* __restrict__ b1, const float* __restrict__ w2,
    _Float16* __restrict__ Kf, _Float16* __restrict__ Vf,
    float* __restrict__ akT, float* __restrict__ btR) {
    const int bid = blockIdx.x;
    const int tid = threadIdx.x;
    if (bid < NBLK) {
        __shared__ float Vls[64 * 65];   // [d][k] transposed, pad 65
        __shared__ __align__(16) float Kls[64 * 64];  // [k][granule-XOR-swizzled d]
        const int bh = bid / NQT, kt = bid % NQT;
        const size_t base = (size_t)bh * (N_ * D_);
        const int k0 = kt * 64;
        // ---- coalesced row reads: V -> transposed scatter, K -> swizzled linear
#pragma unroll
        for (int it = 0; it < 4; ++it) {
            const int idx = it * 256 + tid;
            const int kr = idx >> 4, c4 = (idx & 15) << 2;
            const int kg = k0 + kr;
            float4 v4 = make_float4(0, 0, 0, 0), k4 = v4;
            if (kg < N_) {
                v4 = *(const float4*)(V + base + (size_t)kg * D_ + c4);
                k4 = *(const float4*)(K + base + (size_t)kg * D_ + c4);
            }
            Vls[(c4 + 0) * 65 + kr] = v4.x;
            Vls[(c4 + 1) * 65 + kr] = v4.y;
            Vls[(c4 + 2) * 65 + kr] = v4.z;
            Vls[(c4 + 3) * 65 + kr] = v4.w;
            const int gi = (c4 >> 2) ^ (kr & 15);  // bijective per row, keeps alignment
            *(float4*)&Kls[kr * 64 + (gi << 2)] = k4;
        }
        if (tid < 64) {
            const int kk = k0 + tid;
            const int h = bh % H_;
            const float sgl = LOG2E / (1.f + __expf(-GAMMA[h]));
            float a = 0.f;
            if (kk >= 1 && kk < N_) a = sgl * MU[((size_t)bh * 2 + 1) * N_ + kk];
            akT[bh * 1088 + kk] = a;
        }
        __syncthreads();
        const int lane = tid & 63, lq = lane & 15, g = lane >> 4;
        const int fbh = tid >> 6;
        const size_t tb = (size_t)(bh * NQT + kt) * 4096;
#pragma unroll
        for (int x = 0; x < 2; ++x) {
            const int fb = fbh + x * 4;
            {   // V fragment fb = kh*4+dg from Vls
                const int kh = fb >> 2, dg = fb & 3;
                const float* vp = &Vls[(dg * 16 + lq) * 65 + kh * 32 + g * 8];
                half8 v8;
#pragma unroll
                for (int j = 0; j < 8; ++j) v8[j] = (_Float16)vp[j];
                *(half8*)&Vf[tb + fb * 512 + lane * 8] = v8;
            }
            {   // K fragment fb = kg2*2+dh from Kls (2 x b128, unswizzle granules)
                const int row = (fb >> 1) * 16 + lq;
                const int col = (fb & 1) * 32 + g * 8;
                const int ga = ((col >> 2) + 0) ^ (row & 15);
                const int gb = ((col >> 2) + 1) ^ (row & 15);
                f32x4 a = *(const f32x4*)&Kls[row * 64 + (ga << 2)];
                f32x4 b = *(const f32x4*)&Kls[row * 64 + (gb << 2)];
                half8 k8;
                k8[0] = (_Float16)a[0]; k8[1] = (_Float16)a[1];
                k8[2] = (_Float16)a[2]; k8[3] = (_Float16)a[3];
                k8[4] = (_Float16)b[0]; k8[5] = (_Float16)b[1];
                k8[6] = (_Float16)b[2]; k8[7] = (_Float16)b[3];
                *(half8*)&Kf[tb + fb * 512 + lane * 8] = k8;
            }
        }
    } else {
        const int i = (bid - NBLK) * 256 + tid;
        if (i < TBL_) {
            const float x0 = rel[2 * i + 0], x1 = rel[2 * i + 1];
            float acc[H_];
#pragma unroll
            for (int h = 0; h < H_; ++h) acc[h] = 0.f;
#pragma unroll
            for (int j = 0; j < HID_; ++j) {
                float t = fmaf(x0, w1[j], fmaf(x1, w1[HID_ + j], b1[j]));
                float gl = 0.5f * t * (1.f + erff(t * 0.7071067811865475f));  // exact gelu
#pragma unroll
                for (int h = 0; h < H_; ++h) acc[h] = fmaf(gl, w2[j * H_ + h], acc[h]);
            }
#pragma unroll
            for (int h = 0; h < H_; ++h) btR[h * TBL_ + (TBL_ - 1 - i)] = acc[h];
        }
    }
}

// ---------------- fused flash attention, f16 MFMA, DMA-staged fragment tiles
// (round-12 structure, byte-exact) + quad-vectorized bias gathers (reversed table)
__global__ __launch_bounds__(256, 4) void flex_attn(
    const float* __restrict__ Q, const _Float16* __restrict__ Kf,
    const _Float16* __restrict__ Vf, const float* __restrict__ MU,
    const float* __restrict__ GAMMA, const char* __restrict__ btb,  // = ws + BTR_OFF
    const float* __restrict__ akT, float* __restrict__ OUT) {
    __shared__ __align__(16) _Float16 Ks[2][4096];
    __shared__ __align__(16) _Float16 Vs[2][4096];
    __shared__ __align__(16) _Float16 Pl[4][1024];  // [wave][16 q][64 k] XOR-swizzled

    const int bid = blockIdx.x;
    const int swz0 = (bid & 7) * (NBLK / 8) + (bid >> 3);  // bijective XCD swizzle
    const int bh = swz0 / NQT;
    const int qt = swz0 % NQT;
    const int h = bh % H_;
    const int tid = threadIdx.x;
    const int w = tid >> 6;
    const int lane = tid & 63;
    const int lq = lane & 15;
    const int g = lane >> 4;

    const size_t base = (size_t)bh * (N_ * D_);
    const float sg = LOG2E / (1.f + __expf(-GAMMA[h]));

    const int qrow = qt * 64 + w * 16 + lq;
    const bool qv = qrow < N_;

    // Q fragment (B-operand of swapped QK^T), scale = log2e/sqrt(64)
    half8 qf[2];
#pragma unroll
    for (int dh = 0; dh < 2; ++dh) {
        float4 t0 = make_float4(0, 0, 0, 0), t1 = t0;
        if (qv) {
            const float4* qp = (const float4*)(Q + base + (size_t)qrow * D_ + dh * 32 + g * 8);
            t0 = qp[0]; t1 = qp[1];
        }
        const float qs = 0.125f * LOG2E;
        half8 q8;
        q8[0] = (_Float16)(t0.x * qs); q8[1] = (_Float16)(t0.y * qs);
        q8[2] = (_Float16)(t0.z * qs); q8[3] = (_Float16)(t0.w * qs);
        q8[4] = (_Float16)(t1.x * qs); q8[5] = (_Float16)(t1.y * qs);
        q8[6] = (_Float16)(t1.z * qs); q8[7] = (_Float16)(t1.w * qs);
        qf[dh] = q8;
    }

    const bool qb = qv && (qrow >= 1);
    const float qbf = qb ? 1.f : 0.f;
    float aq = 0.f;
    int cq = 0;
    if (qb) {
        const int pq = qrow - 1;
        cq = (pq >> 5) * 63 + (pq & 31);
        aq = sg * MU[(size_t)bh * 2 * N_ + qrow];  // sg*log2e*mu_q
    }
    // REVERSED table: value(ck) = btR[h*TBL + 1984 - cq + ck] -> forward-consecutive
    // in ck. Per-kg quad r=0..3 has ck consecutive except the quads starting at
    // pk0 % 32 == 31 (exactly g==0 && kg even): there ck(r1) = ck(r0)+32.
    // Per-tile recurrence: ck += 126 -> byte offset += 504.
    int boff4[4];
#pragma unroll
    for (int kg = 0; kg < 4; ++kg) {
        const int pk0 = kg * 16 + g * 4 - 1;              // tile 0
        const int ck0 = (pk0 >> 5) * 63 + (pk0 & 31);     // arith shift: ck0(-1) = -32
        boff4[kg] = (h * TBL_ + 1984 - cq + ck0) * 4;
    }
    const float* akb = akT + bh * 1088;
    const _Float16* kfb = Kf + (size_t)bh * NQT * 4096;
    const _Float16* vfb = Vf + (size_t)bh * NQT * 4096;

    f32x4 o[4];
    const f32x4 zz = {0.f, 0.f, 0.f, 0.f};
#pragma unroll
    for (int dg = 0; dg < 4; ++dg) o[dg] = zz;
    float m = 0.f, lsum = 0.f;

    // prologue: stage tile 0 into buf 0
    stage16(kfb + (2 * w + 0) * 512 + lane * 8, &Ks[0][(2 * w + 0) * 512]);
    stage16(kfb + (2 * w + 1) * 512 + lane * 8, &Ks[0][(2 * w + 1) * 512]);
    stage16(vfb + (2 * w + 0) * 512 + lane * 8, &Vs[0][(2 * w + 0) * 512]);
    stage16(vfb + (2 * w + 1) * 512 + lane * 8, &Vs[0][(2 * w + 1) * 512]);
    __syncthreads();

    const int pswz = (lq & 7) << 4;
    char* plw = (char*)&Pl[w][0];

    for (int t = 0; t < NQT; ++t) {
        const int buf = t & 1;
        const int kt0 = t * 64;

        // ---- bias gathers: 1 float4 (+1 dword for crossing quads) per kg
        float bt16[16];
#pragma unroll
        for (int kg = 0; kg < 4; ++kg) {
            const int off = boff4[kg];
            if (kg & 1) {  // never crosses a 32-row boundary
                f32x4u f4 = *(const f32x4u*)(btb + off);
                bt16[kg * 4 + 0] = f4[0];
                bt16[kg * 4 + 1] = f4[1];
                bt16[kg * 4 + 2] = f4[2];
                bt16[kg * 4 + 3] = f4[3];
            } else {       // g==0 lanes cross: r0 separate, r1..r3 at +32 elements
                const bool cross = (g == 0);
                f32x4u f4 = *(const f32x4u*)(btb + off + (cross ? 128 : 0));
                const float s0v = *(const float*)(btb + off);
                bt16[kg * 4 + 0] = s0v;
                bt16[kg * 4 + 1] = cross ? f4[0] : f4[1];
                bt16[kg * 4 + 2] = cross ? f4[1] : f4[2];
                bt16[kg * 4 + 3] = cross ? f4[2] : f4[3];
            }
            boff4[kg] += 504;
        }
        // ---- gate k-terms (vectorized, r-consecutive)
        f32x4 akq[4];
#pragma unroll
        for (int kg = 0; kg < 4; ++kg)
            akq[kg] = *(const f32x4*)(akb + kt0 + kg * 16 + g * 4);

        // ---- stage next tile into the other buffer
        if (t + 1 < NQT) {
            const _Float16* kn = kfb + (size_t)(t + 1) * 4096;
            const _Float16* vn = vfb + (size_t)(t + 1) * 4096;
            stage16(kn + (2 * w + 0) * 512 + lane * 8, &Ks[buf ^ 1][(2 * w + 0) * 512]);
            stage16(kn + (2 * w + 1) * 512 + lane * 8, &Ks[buf ^ 1][(2 * w + 1) * 512]);
            stage16(vn + (2 * w + 0) * 512 + lane * 8, &Vs[buf ^ 1][(2 * w + 0) * 512]);
            stage16(vn + (2 * w + 1) * 512 + lane * 8, &Vs[buf ^ 1][(2 * w + 1) * 512]);
        }

        // ---- QK^T (swapped): C[k][q]; A-frags contiguous-by-lane (conflict-free)
        const _Float16* ksl = &Ks[buf][lane * 8];
        f32x4 sa[4];
#pragma unroll
        for (int kg = 0; kg < 4; ++kg) {
            half8 a0 = *(const half8*)(ksl + (2 * kg + 0) * 512);
            half8 a1 = *(const half8*)(ksl + (2 * kg + 1) * 512);
            f32x4 z = zz;
            z = __builtin_amdgcn_mfma_f32_16x16x32_f16(a0, qf[0], z, 0, 0, 0);
            z = __builtin_amdgcn_mfma_f32_16x16x32_f16(a1, qf[1], z, 0, 0, 0);
            sa[kg] = z;
        }

        // ---- scores (log2 domain): s = sa + (qbf*ak + aq)*bt
        if (t == 0 && g == 0) bt16[0] = 0.f;  // k=0 column has no bias
        float s[16];
#pragma unroll
        for (int kg = 0; kg < 4; ++kg) {
#pragma unroll
            for (int r = 0; r < 4; ++r) {
                const int i = kg * 4 + r;
                s[i] = fmaf(fmaf(qbf, akq[kg][r], aq), bt16[i], sa[kg][r]);
            }
        }
        if (t == NQT - 1) {  // mask k >= N (only k=1024 = i0,g0 survives)
#pragma unroll
            for (int kg = 0; kg < 4; ++kg)
#pragma unroll
                for (int r = 0; r < 4; ++r) {
                    const int i = kg * 4 + r;
                    if (1024 + kg * 16 + g * 4 + r >= N_) s[i] = -1e30f;
                }
        }

        // ---- defer-max online softmax: no cross-lane work in the common path
        float lmax = s[0];
#pragma unroll
        for (int i = 1; i < 16; ++i) lmax = fmaxf(lmax, s[i]);
        if (t == 0) {
            float mt = fmaxf(lmax, __shfl_xor(lmax, 16));
            m = fmaxf(mt, __shfl_xor(mt, 32));
        } else if (!__all(lmax <= m + THR_)) {
            float mt = fmaxf(lmax, __shfl_xor(lmax, 16));
            mt = fmaxf(mt, __shfl_xor(mt, 32));
            const float mnew = fmaxf(m, mt);
            const float cc = EX2(m - mnew);
            m = mnew;
            lsum *= cc;
            float cc4[4];
#pragma unroll
            for (int r = 0; r < 4; ++r) cc4[r] = __shfl(cc, g * 4 + r);
#pragma unroll
            for (int dg = 0; dg < 4; ++dg)
#pragma unroll
                for (int r = 0; r < 4; ++r) o[dg][r] *= cc4[r];
        }
        float pv16[16];
        float ls0 = 0.f, ls1 = 0.f;
#pragma unroll
        for (int i = 0; i < 16; i += 2) {
            pv16[i] = EX2(s[i] - m);
            pv16[i + 1] = EX2(s[i + 1] - m);
            ls0 += pv16[i];
            ls1 += pv16[i + 1];
        }
        lsum += ls0 + ls1;

        // ---- P -> f16, XOR-swizzled per-wave LDS
#pragma unroll
        for (int kg = 0; kg < 4; ++kg) {
            fp16x2 h0 = __builtin_amdgcn_cvt_pkrtz(pv16[kg * 4 + 0], pv16[kg * 4 + 1]);
            fp16x2 h1 = __builtin_amdgcn_cvt_pkrtz(pv16[kg * 4 + 2], pv16[kg * 4 + 3]);
            uint2 u = make_uint2(__builtin_bit_cast(uint32_t, h0),
                                 __builtin_bit_cast(uint32_t, h1));
            *(uint2*)(plw + lq * 128 + ((kg * 32 + g * 8) ^ pswz)) = u;
        }

        // ---- PV: C[q][d] += P[q][k] V[k][d]
#pragma unroll
        for (int kh = 0; kh < 2; ++kh) {
            half8 pa = *(const half8*)(plw + lq * 128 + ((kh * 64 + g * 16) ^ pswz));
#pragma unroll
            for (int dg = 0; dg < 4; ++dg) {
                half8 vb8 = *(const half8*)&Vs[buf][(kh * 4 + dg) * 512 + lane * 8];
                o[dg] = __builtin_amdgcn_mfma_f32_16x16x32_f16(pa, vb8, o[dg], 0, 0, 0);
            }
        }
        __syncthreads();
    }

    lsum += __shfl_xor(lsum, 16);
    lsum += __shfl_xor(lsum, 32);
    const float linv = 1.f / lsum;
    float li4[4];
#pragma unroll
    for (int r = 0; r < 4; ++r) li4[r] = __shfl(linv, g * 4 + r);
#pragma unroll
    for (int dg = 0; dg < 4; ++dg) {
#pragma unroll
        for (int r = 0; r < 4; ++r) {
            const int qq = qt * 64 + w * 16 + g * 4 + r;
            if (qq < N_) OUT[base + (size_t)qq * D_ + dg * 16 + lq] = o[dg][r] * li4[r];
        }
    }
}

extern "C" void kernel_launch(void* const* d_in, const int* in_sizes, int n_in,
                              void* d_out, int out_size, void* d_ws, size_t ws_size,
                              hipStream_t stream) {
    const float* q = (const float*)d_in[0];
    const float* k = (const float*)d_in[1];
    const float* v = (const float*)d_in[2];
    const float* mu = (const float*)d_in[3];
    const float* w1 = (const float*)d_in[4];
    const float* b1 = (const float*)d_in[5];
    const float* w2 = (const float*)d_in[6];
    const float* gamma = (const float*)d_in[7];
    const float* rel = (const float*)d_in[8];
    // d_in[9] = idx_table: reconstructed analytically, never read.

    char* ws = (char*)d_ws;
    float* akT = (float*)(ws + AKT_OFF);
    float* btR = (float*)(ws + BTR_OFF);
    _Float16* Kf = (_Float16*)(ws + KF_OFF);
    _Float16* Vf = (_Float16*)(ws + VF_OFF);

    prep<<<NBLK + (TBL_ + 255) / 256, 256, 0, stream>>>(k, v, mu, gamma, rel, w1, b1, w2,
                                                        Kf, Vf, akT, btR);
    flex_attn<<<NBLK, 256, 0, stream>>>(q, Kf, Vf, mu, gamma, ws + BTR_OFF, akT,
                                        (float*)d_out);
}